// Round 1
// baseline (1141.993 us; speedup 1.0000x reference)
//
#include <hip/hip_runtime.h>

#define NN 100000
#define NE 500000
#define D 128
#define EPS 1e-5f
#define SLOPE 0.01f

// ---------------- CSR build ----------------
__global__ void count_deg(const int* __restrict__ dst, int E, int* __restrict__ deg) {
  int i = blockIdx.x * 256 + threadIdx.x;
  if (i < E) atomicAdd(&deg[dst[i]], 1);
}

__global__ void scan_block_sums(const int* __restrict__ deg, int* __restrict__ bsums, int n) {
  __shared__ int red[256];
  int base = blockIdx.x * 1024;
  int s = 0;
  for (int i = threadIdx.x; i < 1024; i += 256) {
    int idx = base + i;
    if (idx < n) s += deg[idx];
  }
  red[threadIdx.x] = s;
  __syncthreads();
  for (int off = 128; off > 0; off >>= 1) {
    if (threadIdx.x < off) red[threadIdx.x] += red[threadIdx.x + off];
    __syncthreads();
  }
  if (threadIdx.x == 0) bsums[blockIdx.x] = red[0];
}

__global__ void scan_top(int* bsums, int nb) {
  if (threadIdx.x == 0 && blockIdx.x == 0) {
    int run = 0;
    for (int i = 0; i < nb; ++i) { int v = bsums[i]; bsums[i] = run; run += v; }
  }
}

__global__ void scan_final(const int* __restrict__ deg, const int* __restrict__ bsums,
                           int* __restrict__ row_ptr, int* __restrict__ fill,
                           float* __restrict__ invdeg, int n, int Etot) {
  __shared__ int buf[2][256];
  int base = blockIdx.x * 1024;
  int v[4];
  int s = 0;
#pragma unroll
  for (int j = 0; j < 4; ++j) {
    int idx = base + threadIdx.x * 4 + j;
    v[j] = (idx < n) ? deg[idx] : 0;
    s += v[j];
  }
  buf[0][threadIdx.x] = s;
  __syncthreads();
  int cur = 0;
  for (int d2 = 1; d2 < 256; d2 <<= 1) {
    int val = buf[cur][threadIdx.x];
    if (threadIdx.x >= d2) val += buf[cur][threadIdx.x - d2];
    buf[cur ^ 1][threadIdx.x] = val;
    __syncthreads();
    cur ^= 1;
  }
  int run = buf[cur][threadIdx.x] - s + bsums[blockIdx.x];
#pragma unroll
  for (int j = 0; j < 4; ++j) {
    int idx = base + threadIdx.x * 4 + j;
    if (idx < n) {
      row_ptr[idx] = run;
      fill[idx] = run;
      int dv = v[j] < 1 ? 1 : v[j];
      invdeg[idx] = 1.0f / (float)dv;
      run += v[j];
    }
  }
  if (blockIdx.x == 0 && threadIdx.x == 0) row_ptr[n] = Etot;
}

__global__ void fill_csr(const int* __restrict__ src, const int* __restrict__ dst,
                         int* __restrict__ fill, int* __restrict__ col, int E) {
  int i = blockIdx.x * 256 + threadIdx.x;
  if (i < E) {
    int p = atomicAdd(&fill[dst[i]], 1);
    col[p] = src[i];
  }
}

// ---------------- small utils ----------------
__global__ void add_mats(const float* __restrict__ a, const float* __restrict__ b,
                         float* __restrict__ o, int n) {
  int i = blockIdx.x * 256 + threadIdx.x;
  if (i < n) o[i] = a[i] + b[i];
}

// ---------------- GEMM: Y[M,128] = X[M,128] @ W[128,128], fp32 ----------------
// One row per thread; acc[128] in VGPRs; W indexed wave-uniformly -> s_load (SMEM pipe).
__global__ __launch_bounds__(256) void sgemm128(const float* __restrict__ X,
                                                const float* __restrict__ W,
                                                float* __restrict__ Y, int M) {
  int row = blockIdx.x * 256 + threadIdx.x;
  if (row >= M) return;
  const float* x = X + (size_t)row * D;
  float acc[D];
#pragma unroll
  for (int c = 0; c < D; ++c) acc[c] = 0.0f;
#pragma unroll 1
  for (int k = 0; k < D; k += 4) {
    float4 xv = *reinterpret_cast<const float4*>(x + k);
    float xs[4] = {xv.x, xv.y, xv.z, xv.w};
#pragma unroll
    for (int kk = 0; kk < 4; ++kk) {
      const float* wr = W + (size_t)(k + kk) * D;  // wave-uniform address
#pragma unroll
      for (int c = 0; c < D; c += 4) {
        float4 wv = *reinterpret_cast<const float4*>(wr + c);
        acc[c + 0] = fmaf(xs[kk], wv.x, acc[c + 0]);
        acc[c + 1] = fmaf(xs[kk], wv.y, acc[c + 1]);
        acc[c + 2] = fmaf(xs[kk], wv.z, acc[c + 2]);
        acc[c + 3] = fmaf(xs[kk], wv.w, acc[c + 3]);
      }
    }
  }
  float* y = Y + (size_t)row * D;
#pragma unroll
  for (int c = 0; c < D; c += 4) {
    float4 o;
    o.x = acc[c]; o.y = acc[c + 1]; o.z = acc[c + 2]; o.w = acc[c + 3];
    *reinterpret_cast<float4*>(y + c) = o;
  }
}

// ---------------- mean aggregation (gather via CSR): C[n] += inv[n]*sum_j H[col[j]] ----
__global__ void aggregate(float* __restrict__ C, const float* __restrict__ H,
                          const int* __restrict__ row_ptr, const int* __restrict__ col,
                          const float* __restrict__ invdeg) {
  int n = blockIdx.x;
  int beg = row_ptr[n], end = row_ptr[n + 1];
  if (beg == end) return;
  int t = threadIdx.x;  // 0..63, each lane owns features 2t, 2t+1
  float s0 = 0.f, s1 = 0.f;
  int j = beg;
  for (; j + 1 < end; j += 2) {
    int c0 = col[j], c1 = col[j + 1];
    float2 a = *reinterpret_cast<const float2*>(H + (size_t)c0 * D + 2 * t);
    float2 b = *reinterpret_cast<const float2*>(H + (size_t)c1 * D + 2 * t);
    s0 += a.x + b.x;
    s1 += a.y + b.y;
  }
  if (j < end) {
    int c0 = col[j];
    float2 a = *reinterpret_cast<const float2*>(H + (size_t)c0 * D + 2 * t);
    s0 += a.x;
    s1 += a.y;
  }
  float inv = invdeg[n];
  float2* cp = reinterpret_cast<float2*>(C + (size_t)n * D + 2 * t);
  float2 cv = *cp;
  cv.x += s0 * inv;
  cv.y += s1 * inv;
  *cp = cv;
}

// ---------------- BatchNorm ----------------
__global__ void bn_stats(const float* __restrict__ H, float* __restrict__ stats, int M) {
  int c = threadIdx.x & (D - 1);
  int half = threadIdx.x >> 7;  // 0 or 1
  int r = blockIdx.x * 256 + half;
  float s = 0.f, s2 = 0.f;
#pragma unroll 4
  for (int i = 0; i < 128; ++i, r += 2) {
    if (r < M) {
      float v = H[(size_t)r * D + c];
      s += v;
      s2 += v * v;
    }
  }
  atomicAdd(&stats[c], s);
  atomicAdd(&stats[D + c], s2);
}

__global__ void bn_apply(const float* __restrict__ H, const float* __restrict__ stats,
                         const float* __restrict__ g, const float* __restrict__ b,
                         float* __restrict__ O, int M, float invM, int leaky) {
  int i = blockIdx.x * 256 + threadIdx.x;
  size_t base = (size_t)i * 4;
  if (base >= (size_t)M * D) return;
  int c = (int)(base & (D - 1));
  float4 h = *reinterpret_cast<const float4*>(H + base);
  float hv[4] = {h.x, h.y, h.z, h.w};
  float ov[4];
#pragma unroll
  for (int q = 0; q < 4; ++q) {
    float mean = stats[c + q] * invM;
    float var = stats[D + c + q] * invM - mean * mean;
    float sc = rsqrtf(var + EPS) * g[c + q];
    float sh = b[c + q] - mean * sc;
    float v = hv[q] * sc + sh;
    if (leaky) v = v > 0.f ? v : SLOPE * v;
    ov[q] = v;
  }
  float4 o;
  o.x = ov[0]; o.y = ov[1]; o.z = ov[2]; o.w = ov[3];
  *reinterpret_cast<float4*>(O + base) = o;
}

// ---------------- edge-label dot products ----------------
__global__ void edge_dot(const float* __restrict__ H, const int* __restrict__ ea,
                         const int* __restrict__ eb, float* __restrict__ out, int EL) {
  int t = blockIdx.x * 256 + threadIdx.x;
  int e = t >> 4, l = t & 15;
  if (e >= EL) return;
  const float* ha = H + (size_t)ea[e] * D + l * 8;
  const float* hb = H + (size_t)eb[e] * D + l * 8;
  float4 a0 = *reinterpret_cast<const float4*>(ha);
  float4 a1 = *reinterpret_cast<const float4*>(ha + 4);
  float4 b0 = *reinterpret_cast<const float4*>(hb);
  float4 b1 = *reinterpret_cast<const float4*>(hb + 4);
  float d = a0.x * b0.x + a0.y * b0.y + a0.z * b0.z + a0.w * b0.w +
            a1.x * b1.x + a1.y * b1.y + a1.z * b1.z + a1.w * b1.w;
  d += __shfl_xor(d, 1);
  d += __shfl_xor(d, 2);
  d += __shfl_xor(d, 4);
  d += __shfl_xor(d, 8);
  if (l == 0) out[e] = d;
}

// ---------------- launch ----------------
extern "C" void kernel_launch(void* const* d_in, const int* in_sizes, int n_in,
                              void* d_out, int out_size, void* d_ws, size_t ws_size,
                              hipStream_t stream) {
  const float* x   = (const float*)d_in[0];
  const int* ei1   = (const int*)d_in[1];
  const int* ei2   = (const int*)d_in[2];
  const int* eli   = (const int*)d_in[3];
  const float* W1n1 = (const float*)d_in[4];
  const float* W1s1 = (const float*)d_in[5];
  const float* W1n2 = (const float*)d_in[6];
  const float* W1s2 = (const float*)d_in[7];
  const float* W2n1 = (const float*)d_in[8];
  const float* W2s1 = (const float*)d_in[9];
  const float* W2n2 = (const float*)d_in[10];
  const float* W2s2 = (const float*)d_in[11];
  const float* g1  = (const float*)d_in[12];
  const float* b1  = (const float*)d_in[13];
  const float* g2  = (const float*)d_in[14];
  const float* b2  = (const float*)d_in[15];
  float* out = (float*)d_out;

  const int N = NN, E = NE;
  const int EL = in_sizes[3] / 2;

  char* w = (char*)d_ws;
  float* A  = (float*)w; w += (size_t)N * D * 4;
  float* Bb = (float*)w; w += (size_t)N * D * 4;
  float* C  = (float*)w; w += (size_t)N * D * 4;
  int* deg1 = (int*)w; w += (size_t)N * 4;
  int* deg2 = (int*)w; w += (size_t)N * 4;
  int* rp1  = (int*)w; w += (size_t)(N + 1) * 4;
  int* rp2  = (int*)w; w += (size_t)(N + 1) * 4;
  int* fl1  = (int*)w; w += (size_t)N * 4;
  int* fl2  = (int*)w; w += (size_t)N * 4;
  int* col1 = (int*)w; w += (size_t)E * 4;
  int* col2 = (int*)w; w += (size_t)E * 4;
  int* bsums = (int*)w; w += 256 * 4;
  float* inv1 = (float*)w; w += (size_t)N * 4;
  float* inv2 = (float*)w; w += (size_t)N * 4;
  float* stats = (float*)w; w += 2 * D * 4;
  float* Ws1 = (float*)w; w += (size_t)D * D * 4;
  float* Ws2 = (float*)w; w += (size_t)D * D * 4;

  hipMemsetAsync(deg1, 0, (size_t)2 * N * 4, stream);  // deg1+deg2 contiguous

  int ebk = (E + 255) / 256;
  count_deg<<<ebk, 256, 0, stream>>>(ei1 + E, E, deg1);
  count_deg<<<ebk, 256, 0, stream>>>(ei2 + E, E, deg2);

  int nb = (N + 1023) / 1024;
  scan_block_sums<<<nb, 256, 0, stream>>>(deg1, bsums, N);
  scan_top<<<1, 64, 0, stream>>>(bsums, nb);
  scan_final<<<nb, 256, 0, stream>>>(deg1, bsums, rp1, fl1, inv1, N, E);
  scan_block_sums<<<nb, 256, 0, stream>>>(deg2, bsums, N);
  scan_top<<<1, 64, 0, stream>>>(bsums, nb);
  scan_final<<<nb, 256, 0, stream>>>(deg2, bsums, rp2, fl2, inv2, N, E);

  fill_csr<<<ebk, 256, 0, stream>>>(ei1, ei1 + E, fl1, col1, E);
  fill_csr<<<ebk, 256, 0, stream>>>(ei2, ei2 + E, fl2, col2, E);

  add_mats<<<(D * D + 255) / 256, 256, 0, stream>>>(W1s1, W1s2, Ws1, D * D);
  add_mats<<<(D * D + 255) / 256, 256, 0, stream>>>(W2s1, W2s2, Ws2, D * D);

  int gb = (N + 255) / 256;
  int ab = (int)(((size_t)N * D / 4 + 255) / 256);

  // ---- Layer 1 ----
  sgemm128<<<gb, 256, 0, stream>>>(x, Ws1, C, N);
  sgemm128<<<gb, 256, 0, stream>>>(x, W1n1, Bb, N);
  aggregate<<<N, 64, 0, stream>>>(C, Bb, rp1, col1, inv1);
  sgemm128<<<gb, 256, 0, stream>>>(x, W1n2, Bb, N);
  aggregate<<<N, 64, 0, stream>>>(C, Bb, rp2, col2, inv2);
  hipMemsetAsync(stats, 0, 2 * D * 4, stream);
  bn_stats<<<gb, 256, 0, stream>>>(C, stats, N);
  bn_apply<<<ab, 256, 0, stream>>>(C, stats, g1, b1, A, N, 1.0f / N, 1);

  // ---- Layer 2 ----
  sgemm128<<<gb, 256, 0, stream>>>(A, Ws2, C, N);
  sgemm128<<<gb, 256, 0, stream>>>(A, W2n1, Bb, N);
  aggregate<<<N, 64, 0, stream>>>(C, Bb, rp1, col1, inv1);
  sgemm128<<<gb, 256, 0, stream>>>(A, W2n2, Bb, N);
  aggregate<<<N, 64, 0, stream>>>(C, Bb, rp2, col2, inv2);
  hipMemsetAsync(stats, 0, 2 * D * 4, stream);
  bn_stats<<<gb, 256, 0, stream>>>(C, stats, N);
  bn_apply<<<ab, 256, 0, stream>>>(C, stats, g2, b2, Bb, N, 1.0f / N, 0);

  // ---- edge-label dots ----
  int db = (int)(((size_t)EL * 16 + 255) / 256);
  edge_dot<<<db, 256, 0, stream>>>(Bb, eli, eli + EL, out, EL);
}